// Round 5
// baseline (1683.831 us; speedup 1.0000x reference)
//
#include <hip/hip_runtime.h>

typedef unsigned short u16;
typedef __attribute__((ext_vector_type(8))) short bf16x8;   // 8 bf16 in 4 VGPRs
typedef __attribute__((ext_vector_type(4))) float f32x4;
typedef __attribute__((ext_vector_type(4))) unsigned int u32x4;
typedef __attribute__((ext_vector_type(2))) unsigned int u32x2;

#define MROWS 18      // 1 batch * 18 rows
#define MT 2          // M-tiles of 16
#define SWZ(r,c) ((c) ^ (((r)&7)<<3))   // element-index XOR swizzle for 512B-stride bf16 LDS rows

__device__ inline u16 f2bf(float f){
  unsigned int u = __float_as_uint(f);
  return (u16)((u + 0x7fffu + ((u>>16)&1u)) >> 16);
}
__device__ inline unsigned int packbf(float a, float b){
  return (unsigned int)f2bf(a) | ((unsigned int)f2bf(b)<<16);
}
__device__ inline float bfloat_lo(unsigned int u){ return __uint_as_float(u<<16); }
__device__ inline float bfloat_hi(unsigned int u){ return __uint_as_float(u & 0xffff0000u); }
__device__ inline float bf2f(u16 h){ return __uint_as_float(((unsigned int)h)<<16); }
__device__ inline float wred(float v){
  #pragma unroll
  for (int m=1;m<64;m<<=1) v += __shfl_xor(v, m, 64);
  return v;
}
__device__ inline float silu_f(float x){ return x / (1.f + __expf(-x)); }
__device__ inline f32x4 mfma16(bf16x8 a, bf16x8 b, f32x4 c){
  return __builtin_amdgcn_mfma_f32_16x16x32_bf16(a, b, c, 0, 0, 0);
}

struct Params {
  const float *sigIn;
  const float *bn_g, *bn_b;
  const float *cWq,*cWk,*cWv,*cbq,*cbk,*cbv,*cbias_k,*cbias_v,*cWo,*cbo;
  const float *xbv, *xbias_v, *xbo;
  const float *b1,*b2,*b3;
  const float *g_cas,*b_cas,*g_ff,*b_ff,*g_fin,*b_fin;
  const u16 *Wv,*Wo,*Wq3,*W1b,*W2b,*W3p;
  const float *bias3, *ecr, *mu, *rstd;
  float *out;
};

// ---------------- prep: convert weights to bf16, build fused q-proj weights ----------------
__global__ void k_prep(const float* __restrict__ xWq, const float* __restrict__ xWk,
                       const float* __restrict__ xWv, const float* __restrict__ xWo,
                       const float* __restrict__ xbq, const float* __restrict__ xbk,
                       const float* __restrict__ xbias_k,
                       const float* __restrict__ W1, const float* __restrict__ W2,
                       const float* __restrict__ W3,
                       u16* Wv, u16* Wo, u16* Wq3, u16* W1b, u16* W2b, u16* W3p, float* bias3){
  const int gid = blockIdx.x*blockDim.x + threadIdx.x;
  const int gsz = gridDim.x*blockDim.x;
  for (int i=gid;i<65536;i+=gsz) Wv[i]=f2bf(xWv[i]);
  for (int i=gid;i<65536;i+=gsz) Wo[i]=f2bf(xWo[i]);
  for (int i=gid;i<8192;i+=gsz)  W1b[i]=f2bf(W1[i]);
  for (int i=gid;i<512;i+=gsz)   W2b[i]=f2bf(W2[i]);
  for (int i=gid;i<8192;i+=gsz){ int o=i>>5, k=i&31; W3p[i] = (k<16)? f2bf(W3[o*16+k]) : (u16)0; }
  for (int i=gid;i<8192;i+=gsz){           // Wq3[32][256]: rows 0-7 qw, 8-15 qb, 16-23 q2, 24-31 zero
    int r=i>>8, c=i&255;
    u16 outv = 0;
    if (r<24){
      int h=r&7, sel=r>>3;
      const float* vec = sel==0? xWk : (sel==1? xbk : xbias_k);
      float s=0.f;
      for (int d=0;d<32;++d) s += xWq[(size_t)(h*32+d)*256+c]*vec[h*32+d];
      outv = f2bf(s);
    }
    Wq3[i]=outv;
  }
  for (int i=gid;i<24;i+=gsz){
    int h=i&7, sel=i>>3;
    const float* vec = sel==0? xWk : (sel==1? xbk : xbias_k);
    float s=0.f; for (int d=0;d<32;++d) s += xbq[h*32+d]*vec[h*32+d];
    bias3[i]=s;
  }
}

// ---------------- ec_raw = ctx @ Ws^T + bs ----------------
__global__ void k_ec(const float* __restrict__ ctx, const float* __restrict__ Ws,
                     const float* __restrict__ bs, float* __restrict__ ecr){
  const int wave = threadIdx.x>>6, lane = threadIdx.x&63;
  const int b = blockIdx.x*4 + wave;
  const float* c = ctx + (size_t)b*512 + lane*8;
  const float4 a0 = *(const float4*)c, a1 = *(const float4*)(c+4);
  float cv[8] = {a0.x,a0.y,a0.z,a0.w,a1.x,a1.y,a1.z,a1.w};
  #pragma unroll 1
  for (int j=0;j<18;++j){
    const float* w = Ws + j*512 + lane*8;
    const float4 w0 = *(const float4*)w, w1 = *(const float4*)(w+4);
    float s = cv[0]*w0.x + cv[1]*w0.y + cv[2]*w0.z + cv[3]*w0.w
            + cv[4]*w1.x + cv[5]*w1.y + cv[6]*w1.z + cv[7]*w1.w;
    s = wred(s);
    if (lane==0) ecr[(size_t)b*18 + j] = s + bs[j];
  }
}

// ---------------- deterministic batch-norm stats over B=4096 ----------------
__global__ void k_bn(const float* __restrict__ ecr, float* __restrict__ mu, float* __restrict__ rstd){
  __shared__ float red[256];
  const int tid = threadIdx.x;
  for (int j=0;j<18;++j){
    float s=0.f, s2=0.f;
    for (int b=tid;b<4096;b+=256){ float v = ecr[(size_t)b*18+j]; s+=v; s2+=v*v; }
    red[tid]=s; __syncthreads();
    for (int o=128;o>0;o>>=1){ if(tid<o) red[tid]+=red[tid+o]; __syncthreads(); }
    float S = red[0]; __syncthreads();
    red[tid]=s2; __syncthreads();
    for (int o=128;o>0;o>>=1){ if(tid<o) red[tid]+=red[tid+o]; __syncthreads(); }
    float S2 = red[0]; __syncthreads();
    if (tid==0){ float m = S*(1.f/4096.f); float v = S2*(1.f/4096.f) - m*m;
                 mu[j]=m; rstd[j]=rsqrtf(v+1e-5f); }
  }
}

// ---------------- fused 4-layer decoder, 1 batch / block ----------------
// NOTE: bare launch_bounds(256): sets flat workgroup size (reg budget 512/wave-SIMD at 1 wave min)
// so the allocator can pick a spill-free split; do NOT force min-waves (r2-r4: forcing it spilled
// to scratch, 0.3-0.5 GB of HBM traffic, 1.3x slower than the 61KB/2-block r1 baseline).
__global__ __launch_bounds__(256) void k_main(Params P){
  __shared__ __attribute__((aligned(16))) u16 s_sig[MROWS][256];  // residual stream, bf16, swizzled
  __shared__ __attribute__((aligned(16))) u16 s_ns [MROWS][256];  // ns / ca (shared), bf16, swizzled
  __shared__ __attribute__((aligned(16))) u16 s_v  [MROWS][256];  // v, bf16, swizzled
  __shared__ __attribute__((aligned(16))) u16 s_h1 [MROWS][32];   // FFN hidden (h1 then h2-padded)
  __shared__ float s_qq[MROWS][24];                               // qw | qb | q2 planes
  __shared__ float s_ec[MROWS];
  __shared__ unsigned int s_p[8][MROWS][10];                      // attn weights, bf16-pair packed

  const int tid  = threadIdx.x;
  const int wave = tid >> 6;
  const int lane = tid & 63;
  const int lr   = lane & 15;      // A-row / B-col within 16-tile
  const int lkg  = lane >> 4;      // k-group
  const int kof  = lkg * 8;
  const int dr   = lkg * 4;        // C/D row base: row=(lane>>4)*4+reg
  const int b0   = blockIdx.x;

  // ---- init: sig (f32 global -> bf16 LDS), ec (batch-norm applied)
  for (int idx = tid*8; idx < MROWS*256; idx += 256*8){
    const int row = idx >> 8, col = idx & 255;
    const float* src = P.sigIn + ((size_t)b0*18 + row)*256 + col;
    const float4 a = *(const float4*)src;
    const float4 b = *(const float4*)(src+4);
    u32x4 w;
    w[0]=packbf(a.x,a.y); w[1]=packbf(a.z,a.w);
    w[2]=packbf(b.x,b.y); w[3]=packbf(b.z,b.w);
    *(u32x4*)&s_sig[row][SWZ(row,col)] = w;
  }
  if (tid < MROWS){
    const float raw = P.ecr[(size_t)b0*18 + tid];
    s_ec[tid] = (raw - P.mu[tid]) * P.rstd[tid] * P.bn_g[tid] + P.bn_b[tid];
  }
  __syncthreads();

  auto ln_pass = [&](const float* g, const float* bvec){
    for (int r = wave; r < MROWS; r += 4){
      const int col = lane*4;
      const u32x2 raw = *(const u32x2*)&s_sig[r][SWZ(r,col)];
      const float x0 = bfloat_lo(raw[0]), x1 = bfloat_hi(raw[0]);
      const float x2 = bfloat_lo(raw[1]), x3 = bfloat_hi(raw[1]);
      const float m = wred(x0+x1+x2+x3)*(1.f/256.f);
      const float d0=x0-m, d1=x1-m, d2=x2-m, d3=x3-m;
      const float rs = rsqrtf(wred(d0*d0+d1*d1+d2*d2+d3*d3)*(1.f/256.f)+1e-10f);
      const float4 gv = *(const float4*)(g+col);
      const float4 bv = *(const float4*)(bvec+col);
      u32x2 o;
      o[0] = packbf(d0*rs*gv.x+bv.x, d1*rs*gv.y+bv.y);
      o[1] = packbf(d2*rs*gv.z+bv.z, d3*rs*gv.w+bv.w);
      *(u32x2*)&s_ns[r][SWZ(r,col)] = o;
    }
  };

  for (int layer = 0; layer < 4; ++layer){
    // ---- P0: context self-attention on ec (scalar, dim=1)
    float newec = 0.f;
    if (tid < MROWS){
      const int i = tid;
      const float cwq=P.cWq[0], cbq=P.cbq[0], cwk=P.cWk[0], cbk=P.cbk[0];
      const float cwv=P.cWv[0], cbv=P.cbv[0], ck1=P.cbias_k[0], cv1=P.cbias_v[0];
      const float cwo=P.cWo[0], cbo=P.cbo[0];
      const float qi = s_ec[i]*cwq + cbq;
      float mx = qi*ck1;
      #pragma unroll
      for (int j=0;j<18;++j) mx = fmaxf(mx, qi*(s_ec[j]*cwk + cbk));
      float den=0.f, o=0.f;
      #pragma unroll
      for (int j=0;j<18;++j){
        const float pp=__expf(qi*(s_ec[j]*cwk + cbk)-mx);
        den+=pp; o+=pp*(s_ec[j]*cwv+cbv);
      }
      const float pp=__expf(qi*ck1-mx); den+=pp; o+=pp*cv1;
      newec = s_ec[i] + (o/den)*cwo + cbo;
    }
    __syncthreads();
    if (tid < MROWS) s_ec[tid] = newec;

    // ---- P1: ns = LN(sig) with ln_cas
    ln_pass(P.g_cas, P.b_cas);
    __syncthreads();

    // ---- P2+P3: fused q-proj (ns@Wq3^T) and v (ns@Wv^T + xbv)
    {
      f32x4 accV[MT][4]; f32x4 accQ[MT];
      #pragma unroll
      for (int mt=0;mt<MT;++mt){
        accQ[mt] = f32x4{0.f,0.f,0.f,0.f};
        #pragma unroll
        for (int nt=0;nt<4;++nt) accV[mt][nt] = f32x4{0.f,0.f,0.f,0.f};
      }
      for (int kk=0; kk<8; ++kk){
        const int k0 = kk*32 + kof;
        bf16x8 afr[MT];
        #pragma unroll
        for (int mt=0;mt<MT;++mt){
          const int row = mt*16 + lr;
          u32x4 raw = u32x4{0u,0u,0u,0u};
          if (row < MROWS) raw = *(const u32x4*)&s_ns[row][SWZ(row,k0)];
          afr[mt] = __builtin_bit_cast(bf16x8, raw);
        }
        #pragma unroll
        for (int nt=0;nt<4;++nt){
          const int n = (wave*4+nt)*16 + lr;
          const bf16x8 bfr = __builtin_bit_cast(bf16x8, *(const u32x4*)(P.Wv + (size_t)n*256 + k0));
          #pragma unroll
          for (int mt=0;mt<MT;++mt) accV[mt][nt] = mfma16(afr[mt], bfr, accV[mt][nt]);
        }
        if (wave < 2){
          const bf16x8 bq = __builtin_bit_cast(bf16x8, *(const u32x4*)(P.Wq3 + (size_t)(wave*16+lr)*256 + k0));
          #pragma unroll
          for (int mt=0;mt<MT;++mt) accQ[mt] = mfma16(afr[mt], bq, accQ[mt]);
        }
      }
      #pragma unroll
      for (int nt=0;nt<4;++nt){
        const int n = (wave*4+nt)*16 + lr;
        const float bias = P.xbv[n];
        #pragma unroll
        for (int mt=0;mt<MT;++mt){
          #pragma unroll
          for (int q=0;q<4;++q){
            const int row = mt*16 + dr + q;
            if (row < MROWS) s_v[row][SWZ(row,n)] = f2bf(accV[mt][nt][q] + bias);
          }
        }
      }
      if (wave < 2){
        const int c = wave*16 + lr;
        if (c < 24){
          const float bias = P.bias3[c];
          #pragma unroll
          for (int mt=0;mt<MT;++mt){
            #pragma unroll
            for (int q=0;q<4;++q){
              const int row = mt*16 + dr + q;
              if (row < MROWS) s_qq[row][c] = accQ[mt][q] + bias;
            }
          }
        }
      }
    }
    __syncthreads();

    // ---- P4: attention, register-lean: p -> LDS (bf16 pairs), then 2 chunks of d=16
    // scores rank-1 in position: s_j = qw*ec[j] + qb (pre-scaled); s_18 = q2.
    if (tid < 144){
      const float scale = 0.17677669529663687f; // 1/sqrt(32)
      const int h = tid/18, i = tid - h*18;
      const float qw = s_qq[i][h]*scale, qb = s_qq[i][8+h]*scale, s18 = s_qq[i][16+h]*scale;
      float mx = s18;
      #pragma unroll
      for (int j=0;j<18;++j) mx = fmaxf(mx, qw*s_ec[j] + qb);
      float den = 0.f;
      #pragma unroll
      for (int jj=0;jj<9;++jj){
        const float p0 = __expf(qw*s_ec[2*jj]   + qb - mx);
        const float p1 = __expf(qw*s_ec[2*jj+1] + qb - mx);
        den += p0 + p1;
        s_p[h][i][jj] = packbf(p0, p1);
      }
      const float p18 = __expf(s18 - mx);
      den += p18;
      const float inv = 1.f/den;
      #pragma unroll 1
      for (int dc=0; dc<2; ++dc){
        const int dbase = h*32 + dc*16;
        float acc[16];
        #pragma unroll
        for (int d4=0; d4<4; ++d4){
          const float4 xv = *(const float4*)(P.xbias_v + dbase + d4*4);
          acc[d4*4+0]=p18*xv.x; acc[d4*4+1]=p18*xv.y; acc[d4*4+2]=p18*xv.z; acc[d4*4+3]=p18*xv.w;
        }
        #pragma unroll 1
        for (int jj=0;jj<9;++jj){
          const unsigned int pp = s_p[h][i][jj];
          #pragma unroll
          for (int j2=0;j2<2;++j2){
            const int j = 2*jj + j2;
            const float pj = j2 ? bfloat_hi(pp) : bfloat_lo(pp);
            #pragma unroll
            for (int d8=0; d8<2; ++d8){
              const u32x4 u = *(const u32x4*)&s_v[j][SWZ(j, dbase + d8*8)];
              #pragma unroll
              for (int q=0;q<4;++q){
                acc[d8*8+q*2]   += pj*bfloat_lo(u[q]);
                acc[d8*8+q*2+1] += pj*bfloat_hi(u[q]);
              }
            }
          }
        }
        #pragma unroll
        for (int d8=0; d8<2; ++d8){
          u32x4 w;
          #pragma unroll
          for (int q=0;q<4;++q) w[q] = packbf(acc[d8*8+q*2]*inv, acc[d8*8+q*2+1]*inv);
          *(u32x4*)&s_ns[i][SWZ(i, dbase + d8*8)] = w;   // ca overwrites ns
        }
      }
    }
    __syncthreads();

    // ---- P5: sig += ca @ Wo^T + xbo
    {
      f32x4 acc[MT][4];
      #pragma unroll
      for (int mt=0;mt<MT;++mt){
        #pragma unroll
        for (int nt=0;nt<4;++nt) acc[mt][nt] = f32x4{0.f,0.f,0.f,0.f};
      }
      for (int kk=0; kk<8; ++kk){
        const int k0 = kk*32 + kof;
        bf16x8 afr[MT];
        #pragma unroll
        for (int mt=0;mt<MT;++mt){
          const int row = mt*16 + lr;
          u32x4 raw = u32x4{0u,0u,0u,0u};
          if (row < MROWS) raw = *(const u32x4*)&s_ns[row][SWZ(row,k0)];
          afr[mt] = __builtin_bit_cast(bf16x8, raw);
        }
        #pragma unroll
        for (int nt=0;nt<4;++nt){
          const int n = (wave*4+nt)*16 + lr;
          const bf16x8 bfr = __builtin_bit_cast(bf16x8, *(const u32x4*)(P.Wo + (size_t)n*256 + k0));
          #pragma unroll
          for (int mt=0;mt<MT;++mt) acc[mt][nt] = mfma16(afr[mt], bfr, acc[mt][nt]);
        }
      }
      #pragma unroll
      for (int nt=0;nt<4;++nt){
        const int n = (wave*4+nt)*16 + lr;
        const float bias = P.xbo[n];
        #pragma unroll
        for (int mt=0;mt<MT;++mt){
          #pragma unroll
          for (int q=0;q<4;++q){
            const int row = mt*16 + dr + q;
            if (row < MROWS){
              const int si = SWZ(row,n);
              s_sig[row][si] = f2bf(bf2f(s_sig[row][si]) + acc[mt][nt][q] + bias);
            }
          }
        }
      }
    }
    __syncthreads();

    // ---- P6: nf = LN(sig) with ln_ff
    ln_pass(P.g_ff, P.b_ff);
    __syncthreads();

    // ---- P7: h1 = silu(nf @ W1^T + b1)   (M x 32)
    if (wave < 2){
      f32x4 acc[MT];
      #pragma unroll
      for (int mt=0;mt<MT;++mt) acc[mt] = f32x4{0.f,0.f,0.f,0.f};
      for (int kk=0; kk<8; ++kk){
        const int k0 = kk*32 + kof;
        bf16x8 afr[MT];
        #pragma unroll
        for (int mt=0;mt<MT;++mt){
          const int row = mt*16 + lr;
          u32x4 raw = u32x4{0u,0u,0u,0u};
          if (row < MROWS) raw = *(const u32x4*)&s_ns[row][SWZ(row,k0)];
          afr[mt] = __builtin_bit_cast(bf16x8, raw);
        }
        const bf16x8 bfr = __builtin_bit_cast(bf16x8, *(const u32x4*)(P.W1b + (size_t)(wave*16+lr)*256 + k0));
        #pragma unroll
        for (int mt=0;mt<MT;++mt) acc[mt] = mfma16(afr[mt], bfr, acc[mt]);
      }
      const int c = wave*16 + lr;
      const float bias = P.b1[c];
      #pragma unroll
      for (int mt=0;mt<MT;++mt){
        #pragma unroll
        for (int q=0;q<4;++q){
          const int row = mt*16 + dr + q;
          if (row < MROWS) s_h1[row][c] = f2bf(silu_f(acc[mt][q] + bias));
        }
      }
    }
    __syncthreads();

    // ---- P8: h2 = silu(h1 @ W2^T + b2), back into s_h1 with cols 16..31 zeroed (K-pad)
    if (wave < MT){
      const int row_a = wave*16 + lr;
      u32x4 raw = u32x4{0u,0u,0u,0u};
      if (row_a < MROWS) raw = *(const u32x4*)&s_h1[row_a][kof];
      const bf16x8 a = __builtin_bit_cast(bf16x8, raw);
      const bf16x8 b = __builtin_bit_cast(bf16x8, *(const u32x4*)(P.W2b + (size_t)lr*32 + kof));
      f32x4 acc = mfma16(a, b, f32x4{0.f,0.f,0.f,0.f});
      const float bias = P.b2[lr];
      #pragma unroll
      for (int q=0;q<4;++q){
        const int row = wave*16 + dr + q;
        if (row < MROWS){
          s_h1[row][lr]    = f2bf(silu_f(acc[q] + bias));
          s_h1[row][lr+16] = 0;
        }
      }
    }
    __syncthreads();

    // ---- P9: sig += silu(h2 @ W3p^T + b3)   (K=32 padded from 16)
    {
      bf16x8 afr[MT];
      #pragma unroll
      for (int mt=0;mt<MT;++mt){
        const int row = mt*16 + lr;
        u32x4 raw = u32x4{0u,0u,0u,0u};
        if (row < MROWS) raw = *(const u32x4*)&s_h1[row][kof];
        afr[mt] = __builtin_bit_cast(bf16x8, raw);
      }
      f32x4 acc[MT][4];
      #pragma unroll
      for (int nt=0;nt<4;++nt){
        const int n = (wave*4+nt)*16 + lr;
        const bf16x8 bfr = __builtin_bit_cast(bf16x8, *(const u32x4*)(P.W3p + (size_t)n*32 + kof));
        #pragma unroll
        for (int mt=0;mt<MT;++mt) acc[mt][nt] = mfma16(afr[mt], bfr, f32x4{0.f,0.f,0.f,0.f});
      }
      #pragma unroll
      for (int nt=0;nt<4;++nt){
        const int n = (wave*4+nt)*16 + lr;
        const float b3v = P.b3[n];
        #pragma unroll
        for (int mt=0;mt<MT;++mt){
          #pragma unroll
          for (int q=0;q<4;++q){
            const int row = mt*16 + dr + q;
            if (row < MROWS){
              const int si = SWZ(row,n);
              s_sig[row][si] = f2bf(bf2f(s_sig[row][si]) + silu_f(acc[mt][nt][q] + b3v));
            }
          }
        }
      }
    }
    __syncthreads();
  } // layers

  // ---- final LN -> out (f32)
  {
    for (int r = wave; r < MROWS; r += 4){
      const int col = lane*4;
      const u32x2 raw = *(const u32x2*)&s_sig[r][SWZ(r,col)];
      const float x0 = bfloat_lo(raw[0]), x1 = bfloat_hi(raw[0]);
      const float x2 = bfloat_lo(raw[1]), x3 = bfloat_hi(raw[1]);
      const float m = wred(x0+x1+x2+x3)*(1.f/256.f);
      const float d0=x0-m, d1=x1-m, d2=x2-m, d3=x3-m;
      const float rs = rsqrtf(wred(d0*d0+d1*d1+d2*d2+d3*d3)*(1.f/256.f)+1e-10f);
      const float4 gv = *(const float4*)(P.g_fin+col);
      const float4 bv = *(const float4*)(P.b_fin+col);
      float4 o;
      o.x = d0*rs*gv.x+bv.x; o.y = d1*rs*gv.y+bv.y;
      o.z = d2*rs*gv.z+bv.z; o.w = d3*rs*gv.w+bv.w;
      *(float4*)(P.out + ((size_t)b0*18 + r)*256 + col) = o;
    }
  }
}

extern "C" void kernel_launch(void* const* d_in, const int* in_sizes, int n_in,
                              void* d_out, int out_size, void* d_ws, size_t ws_size,
                              hipStream_t stream) {
  (void)in_sizes; (void)n_in; (void)out_size; (void)ws_size;
  const float* sigIn   = (const float*)d_in[0];
  const float* ctx     = (const float*)d_in[1];
  const float* Ws      = (const float*)d_in[2];
  const float* bs      = (const float*)d_in[3];
  const float* bn_g    = (const float*)d_in[4];
  const float* bn_b    = (const float*)d_in[5];
  const float* cWq     = (const float*)d_in[6];
  const float* cWk     = (const float*)d_in[7];
  const float* cWv     = (const float*)d_in[8];
  const float* cbq     = (const float*)d_in[9];
  const float* cbk     = (const float*)d_in[10];
  const float* cbv     = (const float*)d_in[11];
  const float* cbias_k = (const float*)d_in[12];
  const float* cbias_v = (const float*)d_in[13];
  const float* cWo     = (const float*)d_in[14];
  const float* cbo     = (const float*)d_in[15];
  const float* xWq     = (const float*)d_in[16];
  const float* xWk     = (const float*)d_in[17];
  const float* xWv     = (const float*)d_in[18];
  const float* xbq     = (const float*)d_in[19];
  const float* xbk     = (const float*)d_in[20];
  const float* xbv     = (const float*)d_in[21];
  const float* xbias_k = (const float*)d_in[22];
  const float* xbias_v = (const float*)d_in[23];
  const float* xWo     = (const float*)d_in[24];
  const float* xbo     = (const float*)d_in[25];
  const float* W1      = (const float*)d_in[26];
  const float* b1      = (const float*)d_in[27];
  const float* W2      = (const float*)d_in[28];
  const float* b2      = (const float*)d_in[29];
  const float* W3      = (const float*)d_in[30];
  const float* b3      = (const float*)d_in[31];
  const float* g_ff    = (const float*)d_in[32];
  const float* b_ff    = (const float*)d_in[33];
  const float* g_cas   = (const float*)d_in[34];
  const float* b_cas   = (const float*)d_in[35];
  const float* g_fin   = (const float*)d_in[36];
  const float* b_fin   = (const float*)d_in[37];

  char* ws = (char*)d_ws;
  u16*  Wv    = (u16*)(ws);             // 131072 B
  u16*  Wo    = (u16*)(ws + 131072);    // 131072 B
  u16*  Wq3   = (u16*)(ws + 262144);    // 16384 B
  u16*  W1b   = (u16*)(ws + 278528);    // 16384 B
  u16*  W2b   = (u16*)(ws + 294912);    // 1024 B
  u16*  W3p   = (u16*)(ws + 295936);    // 16384 B
  float* bias3= (float*)(ws + 312320);  // 96 B (pad to 128)
  float* ecr  = (float*)(ws + 312448);  // 294912 B
  float* mu   = (float*)(ws + 607360);  // 72 B (pad)
  float* rstd = (float*)(ws + 607488);  // 72 B

  k_prep<<<dim3(64), dim3(256), 0, stream>>>(xWq, xWk, xWv, xWo, xbq, xbk, xbias_k,
                                             W1, W2, W3, Wv, Wo, Wq3, W1b, W2b, W3p, bias3);
  k_ec<<<dim3(1024), dim3(256), 0, stream>>>(ctx, Ws, bs, ecr);
  k_bn<<<dim3(1), dim3(256), 0, stream>>>(ecr, mu, rstd);

  Params P;
  P.sigIn = sigIn; P.bn_g = bn_g; P.bn_b = bn_b;
  P.cWq=cWq; P.cWk=cWk; P.cWv=cWv; P.cbq=cbq; P.cbk=cbk; P.cbv=cbv;
  P.cbias_k=cbias_k; P.cbias_v=cbias_v; P.cWo=cWo; P.cbo=cbo;
  P.xbv=xbv; P.xbias_v=xbias_v; P.xbo=xbo;
  P.b1=b1; P.b2=b2; P.b3=b3;
  P.g_cas=g_cas; P.b_cas=b_cas; P.g_ff=g_ff; P.b_ff=b_ff; P.g_fin=g_fin; P.b_fin=b_fin;
  P.Wv=Wv; P.Wo=Wo; P.Wq3=Wq3; P.W1b=W1b; P.W2b=W2b; P.W3p=W3p;
  P.bias3=bias3; P.ecr=ecr; P.mu=mu; P.rstd=rstd;
  P.out = (float*)d_out;

  k_main<<<dim3(4096), dim3(256), 0, stream>>>(P);
}

// Round 6
// 1012.725 us; speedup vs baseline: 1.6627x; 1.6627x over previous
//
#include <hip/hip_runtime.h>

typedef unsigned short u16;
typedef __attribute__((ext_vector_type(8))) short bf16x8;   // 8 bf16 in 4 VGPRs
typedef __attribute__((ext_vector_type(4))) float f32x4;
typedef __attribute__((ext_vector_type(4))) unsigned int u32x4;
typedef __attribute__((ext_vector_type(2))) unsigned int u32x2;

#define MROWS 18      // 1 batch * 18 rows
#define MT 2          // M-tiles of 16
// element-index XOR swizzles (bank-conflict breakers), each derived for its row stride:
#define SWZ(r,c)  ((c) ^ (((r)&7)<<3))        // bf16 rows of 256 (512B stride)
#define SWZF(r,c) ((c) ^ ((((r)>>2)&3)<<3))   // f32 rows of 256 (1KB stride); r>>2 because epilogue lane-groups differ by 4 rows
#define SWZV(n,j) ((j) ^ (((n)&3)<<3))        // s_vT rows of 32 u16 (64B stride)
#define SWZP(i,j) ((j) ^ (((i)&3)<<3))        // s_p  rows of 32 u16 (64B stride)

__device__ inline u16 f2bf(float f){
  unsigned int u = __float_as_uint(f);
  return (u16)((u + 0x7fffu + ((u>>16)&1u)) >> 16);
}
__device__ inline unsigned int packbf(float a, float b){
  return (unsigned int)f2bf(a) | ((unsigned int)f2bf(b)<<16);
}
__device__ inline float bfloat_lo(unsigned int u){ return __uint_as_float(u<<16); }
__device__ inline float bfloat_hi(unsigned int u){ return __uint_as_float(u & 0xffff0000u); }
__device__ inline float wred(float v){
  #pragma unroll
  for (int m=1;m<64;m<<=1) v += __shfl_xor(v, m, 64);
  return v;
}
__device__ inline float silu_f(float x){ return x / (1.f + __expf(-x)); }
__device__ inline f32x4 mfma16(bf16x8 a, bf16x8 b, f32x4 c){
  return __builtin_amdgcn_mfma_f32_16x16x32_bf16(a, b, c, 0, 0, 0);
}

struct Params {
  const float *sigIn;
  const float *bn_g, *bn_b;
  const float *cWq,*cWk,*cWv,*cbq,*cbk,*cbv,*cbias_k,*cbias_v,*cWo,*cbo;
  const float *xbv, *xbias_v, *xbo;
  const float *b1,*b2,*b3;
  const float *g_cas,*b_cas,*g_ff,*b_ff,*g_fin,*b_fin;
  const u16 *Wv,*Wo,*Wq3,*W1b,*W2b,*W3p;
  const float *bias3, *ecr, *mu, *rstd;
  float *out;
};

// ---------------- prep: convert weights to bf16, build fused q-proj weights ----------------
__global__ void k_prep(const float* __restrict__ xWq, const float* __restrict__ xWk,
                       const float* __restrict__ xWv, const float* __restrict__ xWo,
                       const float* __restrict__ xbq, const float* __restrict__ xbk,
                       const float* __restrict__ xbias_k,
                       const float* __restrict__ W1, const float* __restrict__ W2,
                       const float* __restrict__ W3,
                       u16* Wv, u16* Wo, u16* Wq3, u16* W1b, u16* W2b, u16* W3p, float* bias3){
  const int gid = blockIdx.x*blockDim.x + threadIdx.x;
  const int gsz = gridDim.x*blockDim.x;
  for (int i=gid;i<65536;i+=gsz) Wv[i]=f2bf(xWv[i]);
  for (int i=gid;i<65536;i+=gsz) Wo[i]=f2bf(xWo[i]);
  for (int i=gid;i<8192;i+=gsz)  W1b[i]=f2bf(W1[i]);
  for (int i=gid;i<512;i+=gsz)   W2b[i]=f2bf(W2[i]);
  for (int i=gid;i<8192;i+=gsz){ int o=i>>5, k=i&31; W3p[i] = (k<16)? f2bf(W3[o*16+k]) : (u16)0; }
  for (int i=gid;i<8192;i+=gsz){           // Wq3[32][256]: rows 0-7 qw, 8-15 qb, 16-23 q2, 24-31 zero
    int r=i>>8, c=i&255;
    u16 outv = 0;
    if (r<24){
      int h=r&7, sel=r>>3;
      const float* vec = sel==0? xWk : (sel==1? xbk : xbias_k);
      float s=0.f;
      for (int d=0;d<32;++d) s += xWq[(size_t)(h*32+d)*256+c]*vec[h*32+d];
      outv = f2bf(s);
    }
    Wq3[i]=outv;
  }
  for (int i=gid;i<24;i+=gsz){
    int h=i&7, sel=i>>3;
    const float* vec = sel==0? xWk : (sel==1? xbk : xbias_k);
    float s=0.f; for (int d=0;d<32;++d) s += xbq[h*32+d]*vec[h*32+d];
    bias3[i]=s;
  }
}

// ---------------- ec_raw = ctx @ Ws^T + bs ----------------
__global__ void k_ec(const float* __restrict__ ctx, const float* __restrict__ Ws,
                     const float* __restrict__ bs, float* __restrict__ ecr){
  const int wave = threadIdx.x>>6, lane = threadIdx.x&63;
  const int b = blockIdx.x*4 + wave;
  const float* c = ctx + (size_t)b*512 + lane*8;
  const float4 a0 = *(const float4*)c, a1 = *(const float4*)(c+4);
  float cv[8] = {a0.x,a0.y,a0.z,a0.w,a1.x,a1.y,a1.z,a1.w};
  #pragma unroll 1
  for (int j=0;j<18;++j){
    const float* w = Ws + j*512 + lane*8;
    const float4 w0 = *(const float4*)w, w1 = *(const float4*)(w+4);
    float s = cv[0]*w0.x + cv[1]*w0.y + cv[2]*w0.z + cv[3]*w0.w
            + cv[4]*w1.x + cv[5]*w1.y + cv[6]*w1.z + cv[7]*w1.w;
    s = wred(s);
    if (lane==0) ecr[(size_t)b*18 + j] = s + bs[j];
  }
}

// ---------------- deterministic batch-norm stats over B=4096 ----------------
__global__ void k_bn(const float* __restrict__ ecr, float* __restrict__ mu, float* __restrict__ rstd){
  __shared__ float red[256];
  const int tid = threadIdx.x;
  for (int j=0;j<18;++j){
    float s=0.f, s2=0.f;
    for (int b=tid;b<4096;b+=256){ float v = ecr[(size_t)b*18+j]; s+=v; s2+=v*v; }
    red[tid]=s; __syncthreads();
    for (int o=128;o>0;o>>=1){ if(tid<o) red[tid]+=red[tid+o]; __syncthreads(); }
    float S = red[0]; __syncthreads();
    red[tid]=s2; __syncthreads();
    for (int o=128;o>0;o>>=1){ if(tid<o) red[tid]+=red[tid+o]; __syncthreads(); }
    float S2 = red[0]; __syncthreads();
    if (tid==0){ float m = S*(1.f/4096.f); float v = S2*(1.f/4096.f) - m*m;
                 mu[j]=m; rstd[j]=rsqrtf(v+1e-5f); }
  }
}

// ---------------- fused 4-layer decoder, 1 batch / block, 2 blocks/CU ----------------
// launch_bounds(256,2): r1's proven spill-free point. r2-r4: forcing 3-4 blocks spilled
// (0.3-0.5 GB scratch HBM traffic); r5: bare bound -> >256 regs/wave -> 1 wave/SIMD (occ 12%).
__global__ __launch_bounds__(256, 2) void k_main(Params P){
  __shared__ __attribute__((aligned(16))) float s_sig[MROWS][256];  // residual stream, f32, SWZF
  __shared__ __attribute__((aligned(16))) u16 s_ns [MROWS][256];    // ns / ca (shared), bf16, SWZ
  __shared__ __attribute__((aligned(16))) u16 s_vT [256][32];       // V^T (+ xbias_v at k=18), bf16, SWZV
  __shared__ __attribute__((aligned(16))) u16 s_p  [8][MROWS][32];  // unnormalized softmax P, bf16, SWZP
  __shared__ __attribute__((aligned(16))) u16 s_h1 [MROWS][32];     // FFN hidden (h1 then h2-padded)
  __shared__ float s_qq[MROWS][24];                                 // qw | qb | q2 planes
  __shared__ float s_ec[MROWS];
  __shared__ float s_inv[8][MROWS];                                 // 1/den per (head,row)

  const int tid  = threadIdx.x;
  const int wave = tid >> 6;
  const int lane = tid & 63;
  const int lr   = lane & 15;      // A-row / B-col within 16-tile
  const int lkg  = lane >> 4;      // k-group
  const int kof  = lkg * 8;
  const int dr   = lkg * 4;        // C/D row base: row=(lane>>4)*4+reg
  const int b0   = blockIdx.x;

  // ---- init: sig (f32 global -> f32 LDS), ec (batch-norm applied), pad zeroing
  for (int idx = tid*4; idx < MROWS*256; idx += 256*4){
    const int row = idx >> 8, col = idx & 255;
    const float4 a = *(const float4*)(P.sigIn + (size_t)b0*18*256 + idx);
    *(float4*)&s_sig[row][SWZF(row,col)] = a;
  }
  {
    // s_vT pad cols 18..31: zero (0xAA poison x P=0 would be NaN in MFMA), then k=18 row = xbias_v
    const int n = tid;
    #pragma unroll
    for (int jp=9; jp<16; ++jp) *(unsigned int*)&s_vT[n][SWZV(n,2*jp)] = 0u;
    s_vT[n][SWZV(n,18)] = f2bf(P.xbias_v[n]);
  }
  if (lane < 36){
    // s_p pad cols 20..31: zero once (cols 0..19 rewritten every layer)
    const int h = 2*wave + (lane>=18 ? 1:0);
    const int i = lane - (lane>=18 ? 18:0);
    #pragma unroll
    for (int jp=10; jp<16; ++jp) *(unsigned int*)&s_p[h][i][SWZP(i,2*jp)] = 0u;
  }
  if (tid < MROWS){
    const float raw = P.ecr[(size_t)b0*18 + tid];
    s_ec[tid] = (raw - P.mu[tid]) * P.rstd[tid] * P.bn_g[tid] + P.bn_b[tid];
  }
  __syncthreads();

  auto ln_pass = [&](const float* g, const float* bvec){
    for (int r = wave; r < MROWS; r += 4){
      const int col = lane*4;
      const float4 x = *(const float4*)&s_sig[r][SWZF(r,col)];
      const float m = wred(x.x+x.y+x.z+x.w)*(1.f/256.f);
      const float d0=x.x-m, d1=x.y-m, d2=x.z-m, d3=x.w-m;
      const float rs = rsqrtf(wred(d0*d0+d1*d1+d2*d2+d3*d3)*(1.f/256.f)+1e-10f);
      const float4 gv = *(const float4*)(g+col);
      const float4 bv = *(const float4*)(bvec+col);
      u32x2 o;
      o[0] = packbf(d0*rs*gv.x+bv.x, d1*rs*gv.y+bv.y);
      o[1] = packbf(d2*rs*gv.z+bv.z, d3*rs*gv.w+bv.w);
      *(u32x2*)&s_ns[r][SWZ(r,col)] = o;
    }
  };

  for (int layer = 0; layer < 4; ++layer){
    // ---- P0: context self-attention on ec (scalar, dim=1)
    float newec = 0.f;
    if (tid < MROWS){
      const int i = tid;
      const float cwq=P.cWq[0], cbq=P.cbq[0], cwk=P.cWk[0], cbk=P.cbk[0];
      const float cwv=P.cWv[0], cbv=P.cbv[0], ck1=P.cbias_k[0], cv1=P.cbias_v[0];
      const float cwo=P.cWo[0], cbo=P.cbo[0];
      const float qi = s_ec[i]*cwq + cbq;
      float mx = qi*ck1;
      #pragma unroll
      for (int j=0;j<18;++j) mx = fmaxf(mx, qi*(s_ec[j]*cwk + cbk));
      float den=0.f, o=0.f;
      #pragma unroll
      for (int j=0;j<18;++j){
        const float pp=__expf(qi*(s_ec[j]*cwk + cbk)-mx);
        den+=pp; o+=pp*(s_ec[j]*cwv+cbv);
      }
      const float pp=__expf(qi*ck1-mx); den+=pp; o+=pp*cv1;
      newec = s_ec[i] + (o/den)*cwo + cbo;
    }
    __syncthreads();
    if (tid < MROWS) s_ec[tid] = newec;

    // ---- P1: ns = LN(sig) with ln_cas
    ln_pass(P.g_cas, P.b_cas);
    __syncthreads();

    // ---- P2+P3: fused q-proj (ns@Wq3^T) and v (ns@Wv^T + xbv) -> s_vT (transposed!)
    {
      f32x4 accV[MT][4]; f32x4 accQ[MT];
      #pragma unroll
      for (int mt=0;mt<MT;++mt){
        accQ[mt] = f32x4{0.f,0.f,0.f,0.f};
        #pragma unroll
        for (int nt=0;nt<4;++nt) accV[mt][nt] = f32x4{0.f,0.f,0.f,0.f};
      }
      for (int kk=0; kk<8; ++kk){
        const int k0 = kk*32 + kof;
        bf16x8 afr[MT];
        #pragma unroll
        for (int mt=0;mt<MT;++mt){
          const int row = mt*16 + lr;
          u32x4 raw = u32x4{0u,0u,0u,0u};
          if (row < MROWS) raw = *(const u32x4*)&s_ns[row][SWZ(row,k0)];
          afr[mt] = __builtin_bit_cast(bf16x8, raw);
        }
        #pragma unroll
        for (int nt=0;nt<4;++nt){
          const int n = (wave*4+nt)*16 + lr;
          const bf16x8 bfr = __builtin_bit_cast(bf16x8, *(const u32x4*)(P.Wv + (size_t)n*256 + k0));
          #pragma unroll
          for (int mt=0;mt<MT;++mt) accV[mt][nt] = mfma16(afr[mt], bfr, accV[mt][nt]);
        }
        if (wave < 2){
          const bf16x8 bq = __builtin_bit_cast(bf16x8, *(const u32x4*)(P.Wq3 + (size_t)(wave*16+lr)*256 + k0));
          #pragma unroll
          for (int mt=0;mt<MT;++mt) accQ[mt] = mfma16(afr[mt], bq, accQ[mt]);
        }
      }
      #pragma unroll
      for (int nt=0;nt<4;++nt){
        const int n = (wave*4+nt)*16 + lr;
        const float bias = P.xbv[n];
        #pragma unroll
        for (int mt=0;mt<MT;++mt){
          #pragma unroll
          for (int q=0;q<4;++q){
            const int row = mt*16 + dr + q;
            if (row < MROWS) s_vT[n][SWZV(n,row)] = f2bf(accV[mt][nt][q] + bias);
          }
        }
      }
      if (wave < 2){
        const int c = wave*16 + lr;
        if (c < 24){
          const float bias = P.bias3[c];
          #pragma unroll
          for (int mt=0;mt<MT;++mt){
            #pragma unroll
            for (int q=0;q<4;++q){
              const int row = mt*16 + dr + q;
              if (row < MROWS) s_qq[row][c] = accQ[mt][q] + bias;
            }
          }
        }
      }
    }
    __syncthreads();

    // ---- P4a: softmax weights (wave-local: wave w owns heads 2w, 2w+1)
    // scores rank-1 in position: s_j = qw*ec[j]+qb (pre-scaled); s_18 = q2; p18's V-row is xbias_v.
    if (lane < 36){
      const int h = 2*wave + (lane>=18 ? 1:0);
      const int i = lane - (lane>=18 ? 18:0);
      const float scale = 0.17677669529663687f; // 1/sqrt(32)
      const float qw = s_qq[i][h]*scale, qb = s_qq[i][8+h]*scale, s18 = s_qq[i][16+h]*scale;
      float mx = s18;
      #pragma unroll
      for (int j=0;j<18;++j) mx = fmaxf(mx, qw*s_ec[j] + qb);
      float den = 0.f;
      #pragma unroll
      for (int jj=0;jj<9;++jj){
        const float p0 = __expf(qw*s_ec[2*jj]   + qb - mx);
        const float p1 = __expf(qw*s_ec[2*jj+1] + qb - mx);
        den += p0 + p1;
        *(unsigned int*)&s_p[h][i][SWZP(i,2*jj)] = packbf(p0, p1);
      }
      const float p18 = __expf(s18 - mx); den += p18;
      *(unsigned int*)&s_p[h][i][SWZP(i,18)] = packbf(p18, 0.f);
      s_inv[h][i] = 1.f/den;
    }
    __syncthreads();

    // ---- P4b: ca = (P @ V^T) * inv via MFMA (8 MFMAs/wave; 2 heads/wave), write into s_ns
    #pragma unroll
    for (int hb=0; hb<2; ++hb){
      const int h = wave*2 + hb;
      const bf16x8 a0 = __builtin_bit_cast(bf16x8, *(const u32x4*)&s_p[h][lr][SWZP(lr,kof)]);
      u32x4 zr = u32x4{0u,0u,0u,0u};
      if (lr < 2) zr = *(const u32x4*)&s_p[h][16+lr][SWZP(16+lr,kof)];
      const bf16x8 a1 = __builtin_bit_cast(bf16x8, zr);
      f32x4 d[MT][2];
      #pragma unroll
      for (int nt=0;nt<2;++nt){
        const int vn = h*32 + nt*16 + lr;
        const bf16x8 b = __builtin_bit_cast(bf16x8, *(const u32x4*)&s_vT[vn][SWZV(vn,kof)]);
        d[0][nt] = mfma16(a0, b, f32x4{0.f,0.f,0.f,0.f});
        d[1][nt] = mfma16(a1, b, f32x4{0.f,0.f,0.f,0.f});
      }
      #pragma unroll
      for (int nt=0;nt<2;++nt){
        #pragma unroll
        for (int mt=0;mt<MT;++mt){
          #pragma unroll
          for (int q=0;q<4;++q){
            const int row = mt*16 + dr + q;
            if (row < MROWS){
              s_ns[row][SWZ(row, h*32 + nt*16 + lr)] = f2bf(d[mt][nt][q]*s_inv[h][row]);
            }
          }
        }
      }
    }
    __syncthreads();

    // ---- P5: sig += ca @ Wo^T + xbo   (f32 accumulate in LDS)
    {
      f32x4 acc[MT][4];
      #pragma unroll
      for (int mt=0;mt<MT;++mt){
        #pragma unroll
        for (int nt=0;nt<4;++nt) acc[mt][nt] = f32x4{0.f,0.f,0.f,0.f};
      }
      for (int kk=0; kk<8; ++kk){
        const int k0 = kk*32 + kof;
        bf16x8 afr[MT];
        #pragma unroll
        for (int mt=0;mt<MT;++mt){
          const int row = mt*16 + lr;
          u32x4 raw = u32x4{0u,0u,0u,0u};
          if (row < MROWS) raw = *(const u32x4*)&s_ns[row][SWZ(row,k0)];
          afr[mt] = __builtin_bit_cast(bf16x8, raw);
        }
        #pragma unroll
        for (int nt=0;nt<4;++nt){
          const int n = (wave*4+nt)*16 + lr;
          const bf16x8 bfr = __builtin_bit_cast(bf16x8, *(const u32x4*)(P.Wo + (size_t)n*256 + k0));
          #pragma unroll
          for (int mt=0;mt<MT;++mt) acc[mt][nt] = mfma16(afr[mt], bfr, acc[mt][nt]);
        }
      }
      #pragma unroll
      for (int nt=0;nt<4;++nt){
        const int n = (wave*4+nt)*16 + lr;
        const float bias = P.xbo[n];
        #pragma unroll
        for (int mt=0;mt<MT;++mt){
          #pragma unroll
          for (int q=0;q<4;++q){
            const int row = mt*16 + dr + q;
            if (row < MROWS) s_sig[row][SWZF(row,n)] += acc[mt][nt][q] + bias;
          }
        }
      }
    }
    __syncthreads();

    // ---- P6: nf = LN(sig) with ln_ff
    ln_pass(P.g_ff, P.b_ff);
    __syncthreads();

    // ---- P7: h1 = silu(nf @ W1^T + b1)   (M x 32)
    if (wave < 2){
      f32x4 acc[MT];
      #pragma unroll
      for (int mt=0;mt<MT;++mt) acc[mt] = f32x4{0.f,0.f,0.f,0.f};
      for (int kk=0; kk<8; ++kk){
        const int k0 = kk*32 + kof;
        bf16x8 afr[MT];
        #pragma unroll
        for (int mt=0;mt<MT;++mt){
          const int row = mt*16 + lr;
          u32x4 raw = u32x4{0u,0u,0u,0u};
          if (row < MROWS) raw = *(const u32x4*)&s_ns[row][SWZ(row,k0)];
          afr[mt] = __builtin_bit_cast(bf16x8, raw);
        }
        const bf16x8 bfr = __builtin_bit_cast(bf16x8, *(const u32x4*)(P.W1b + (size_t)(wave*16+lr)*256 + k0));
        #pragma unroll
        for (int mt=0;mt<MT;++mt) acc[mt] = mfma16(afr[mt], bfr, acc[mt]);
      }
      const int c = wave*16 + lr;
      const float bias = P.b1[c];
      #pragma unroll
      for (int mt=0;mt<MT;++mt){
        #pragma unroll
        for (int q=0;q<4;++q){
          const int row = mt*16 + dr + q;
          if (row < MROWS) s_h1[row][c] = f2bf(silu_f(acc[mt][q] + bias));
        }
      }
    }
    __syncthreads();

    // ---- P8: h2 = silu(h1 @ W2^T + b2), back into s_h1 with cols 16..31 zeroed (K-pad)
    if (wave < MT){
      const int row_a = wave*16 + lr;
      u32x4 raw = u32x4{0u,0u,0u,0u};
      if (row_a < MROWS) raw = *(const u32x4*)&s_h1[row_a][kof];
      const bf16x8 a = __builtin_bit_cast(bf16x8, raw);
      const bf16x8 b = __builtin_bit_cast(bf16x8, *(const u32x4*)(P.W2b + (size_t)lr*32 + kof));
      f32x4 acc = mfma16(a, b, f32x4{0.f,0.f,0.f,0.f});
      const float bias = P.b2[lr];
      #pragma unroll
      for (int q=0;q<4;++q){
        const int row = wave*16 + dr + q;
        if (row < MROWS){
          s_h1[row][lr]    = f2bf(silu_f(acc[q] + bias));
          s_h1[row][lr+16] = 0;
        }
      }
    }
    __syncthreads();

    // ---- P9: sig += silu(h2 @ W3p^T + b3)   (K=32 padded from 16)
    {
      bf16x8 afr[MT];
      #pragma unroll
      for (int mt=0;mt<MT;++mt){
        const int row = mt*16 + lr;
        u32x4 raw = u32x4{0u,0u,0u,0u};
        if (row < MROWS) raw = *(const u32x4*)&s_h1[row][kof];
        afr[mt] = __builtin_bit_cast(bf16x8, raw);
      }
      f32x4 acc[MT][4];
      #pragma unroll
      for (int nt=0;nt<4;++nt){
        const int n = (wave*4+nt)*16 + lr;
        const bf16x8 bfr = __builtin_bit_cast(bf16x8, *(const u32x4*)(P.W3p + (size_t)n*32 + kof));
        #pragma unroll
        for (int mt=0;mt<MT;++mt) acc[mt][nt] = mfma16(afr[mt], bfr, f32x4{0.f,0.f,0.f,0.f});
      }
      #pragma unroll
      for (int nt=0;nt<4;++nt){
        const int n = (wave*4+nt)*16 + lr;
        const float b3v = P.b3[n];
        #pragma unroll
        for (int mt=0;mt<MT;++mt){
          #pragma unroll
          for (int q=0;q<4;++q){
            const int row = mt*16 + dr + q;
            if (row < MROWS) s_sig[row][SWZF(row,n)] += silu_f(acc[mt][nt][q] + b3v);
          }
        }
      }
    }
    __syncthreads();
  } // layers

  // ---- final LN -> out (f32)
  {
    for (int r = wave; r < MROWS; r += 4){
      const int col = lane*4;
      const float4 x = *(const float4*)&s_sig[r][SWZF(r,col)];
      const float m = wred(x.x+x.y+x.z+x.w)*(1.f/256.f);
      const float d0=x.x-m, d1=x.y-m, d2=x.z-m, d3=x.w-m;
      const float rs = rsqrtf(wred(d0*d0+d1*d1+d2*d2+d3*d3)*(1.f/256.f)+1e-10f);
      const float4 gv = *(const float4*)(P.g_fin+col);
      const float4 bv = *(const float4*)(P.b_fin+col);
      float4 o;
      o.x = d0*rs*gv.x+bv.x; o.y = d1*rs*gv.y+bv.y;
      o.z = d2*rs*gv.z+bv.z; o.w = d3*rs*gv.w+bv.w;
      *(float4*)(P.out + ((size_t)b0*18 + r)*256 + col) = o;
    }
  }
}

extern "C" void kernel_launch(void* const* d_in, const int* in_sizes, int n_in,
                              void* d_out, int out_size, void* d_ws, size_t ws_size,
                              hipStream_t stream) {
  (void)in_sizes; (void)n_in; (void)out_size; (void)ws_size;
  const float* sigIn   = (const float*)d_in[0];
  const float* ctx     = (const float*)d_in[1];
  const float* Ws      = (const float*)d_in[2];
  const float* bs      = (const float*)d_in[3];
  const float* bn_g    = (const float*)d_in[4];
  const float* bn_b    = (const float*)d_in[5];
  const float* cWq     = (const float*)d_in[6];
  const float* cWk     = (const float*)d_in[7];
  const float* cWv     = (const float*)d_in[8];
  const float* cbq     = (const float*)d_in[9];
  const float* cbk     = (const float*)d_in[10];
  const float* cbv     = (const float*)d_in[11];
  const float* cbias_k = (const float*)d_in[12];
  const float* cbias_v = (const float*)d_in[13];
  const float* cWo     = (const float*)d_in[14];
  const float* cbo     = (const float*)d_in[15];
  const float* xWq     = (const float*)d_in[16];
  const float* xWk     = (const float*)d_in[17];
  const float* xWv     = (const float*)d_in[18];
  const float* xbq     = (const float*)d_in[19];
  const float* xbk     = (const float*)d_in[20];
  const float* xbv     = (const float*)d_in[21];
  const float* xbias_k = (const float*)d_in[22];
  const float* xbias_v = (const float*)d_in[23];
  const float* xWo     = (const float*)d_in[24];
  const float* xbo     = (const float*)d_in[25];
  const float* W1      = (const float*)d_in[26];
  const float* b1      = (const float*)d_in[27];
  const float* W2      = (const float*)d_in[28];
  const float* b2      = (const float*)d_in[29];
  const float* W3      = (const float*)d_in[30];
  const float* b3      = (const float*)d_in[31];
  const float* g_ff    = (const float*)d_in[32];
  const float* b_ff    = (const float*)d_in[33];
  const float* g_cas   = (const float*)d_in[34];
  const float* b_cas   = (const float*)d_in[35];
  const float* g_fin   = (const float*)d_in[36];
  const float* b_fin   = (const float*)d_in[37];

  char* ws = (char*)d_ws;
  u16*  Wv    = (u16*)(ws);             // 131072 B
  u16*  Wo    = (u16*)(ws + 131072);    // 131072 B
  u16*  Wq3   = (u16*)(ws + 262144);    // 16384 B
  u16*  W1b   = (u16*)(ws + 278528);    // 16384 B
  u16*  W2b   = (u16*)(ws + 294912);    // 1024 B
  u16*  W3p   = (u16*)(ws + 295936);    // 16384 B
  float* bias3= (float*)(ws + 312320);  // 96 B (pad to 128)
  float* ecr  = (float*)(ws + 312448);  // 294912 B
  float* mu   = (float*)(ws + 607360);  // 72 B (pad)
  float* rstd = (float*)(ws + 607488);  // 72 B

  k_prep<<<dim3(64), dim3(256), 0, stream>>>(xWq, xWk, xWv, xWo, xbq, xbk, xbias_k,
                                             W1, W2, W3, Wv, Wo, Wq3, W1b, W2b, W3p, bias3);
  k_ec<<<dim3(1024), dim3(256), 0, stream>>>(ctx, Ws, bs, ecr);
  k_bn<<<dim3(1), dim3(256), 0, stream>>>(ecr, mu, rstd);

  Params P;
  P.sigIn = sigIn; P.bn_g = bn_g; P.bn_b = bn_b;
  P.cWq=cWq; P.cWk=cWk; P.cWv=cWv; P.cbq=cbq; P.cbk=cbk; P.cbv=cbv;
  P.cbias_k=cbias_k; P.cbias_v=cbias_v; P.cWo=cWo; P.cbo=cbo;
  P.xbv=xbv; P.xbias_v=xbias_v; P.xbo=xbo;
  P.b1=b1; P.b2=b2; P.b3=b3;
  P.g_cas=g_cas; P.b_cas=b_cas; P.g_ff=g_ff; P.b_ff=b_ff; P.g_fin=g_fin; P.b_fin=b_fin;
  P.Wv=Wv; P.Wo=Wo; P.Wq3=Wq3; P.W1b=W1b; P.W2b=W2b; P.W3p=W3p;
  P.bias3=bias3; P.ecr=ecr; P.mu=mu; P.rstd=rstd;
  P.out = (float*)d_out;

  k_main<<<dim3(4096), dim3(256), 0, stream>>>(P);
}